// Round 2
// baseline (73.165 us; speedup 1.0000x reference)
//
#include <hip/hip_runtime.h>

// Problem constants: B=32, L=4096, C=21, D=512, K=24, LO=8, M=7, TAO=12
#define LL 4096
#define CC 21
#define TT 64          // t-tile per block
#define XSTR 151       // LDS time stride (>= TT+86=150, odd for bank spread)

typedef float v2f __attribute__((ext_vector_type(2)));

__device__ __forceinline__ v2f fma2(v2f a, v2f b, v2f c) {
    return __builtin_elementwise_fma(a, b, c);
}

// Each lane computes an 8-d x 8-t output tile.
// xrow  = &xs[c*XSTR] (LDS, circular x column), wtc = [24][32] weight table
// EDGE: zero-mask wrapped positions tt<84 (tiles t0 in {0,64,4032} only)
template<bool EDGE>
__device__ __forceinline__ void compute_item(
    const float* __restrict__ xrow, const float* __restrict__ wtc,
    const float* __restrict__ biasc, float* __restrict__ outp,
    int o0, int d0, int tg, int t0)
{
    v2f acc[8][4];
    #pragma unroll
    for (int p = 0; p < 4; ++p) {
        v2f bi = { biasc[o0 + 2*p], biasc[o0 + 2*p + 1] };
        #pragma unroll
        for (int ti = 0; ti < 8; ++ti) acc[ti][p] = bi;
    }

    const int tb = tg * 8 + 85;   // LDS slot of (t = t0+tg*8, k=1)

    // mask (EDGE only): v slot s corresponds to conv index t0+tg*8+s-1
    bool msk[10];
    if (EDGE) {
        #pragma unroll
        for (int s = 0; s < 10; ++s)
            msk[s] = (((t0 + tg * 8 + s - 1) & (LL - 1)) < 84);
    }

    #pragma unroll 1
    for (int j = 0; j < 8; ++j) {
        // weights for this j: 3 taps x 8 outputs, 32B-aligned -> 6x ds_read_b128
        const float* wp = &wtc[(j * 3) * 32 + o0];
        float4 w0a = *reinterpret_cast<const float4*>(wp);
        float4 w0b = *reinterpret_cast<const float4*>(wp + 4);
        float4 w1a = *reinterpret_cast<const float4*>(wp + 32);
        float4 w1b = *reinterpret_cast<const float4*>(wp + 36);
        float4 w2a = *reinterpret_cast<const float4*>(wp + 64);
        float4 w2b = *reinterpret_cast<const float4*>(wp + 68);

        // sliding x window: 10 slots cover k=0..2, ti=0..7 for this j
        const float* vp = &xrow[tb - 12 * j - 1];
        float v[10];
        #pragma unroll
        for (int s = 0; s < 10; ++s) {
            float t = vp[s];
            if (EDGE && msk[s]) t = 0.0f;
            v[s] = t;
        }

        #pragma unroll
        for (int ti = 0; ti < 8; ++ti) {
            v2f v0 = { v[ti],     v[ti]     };
            v2f v1 = { v[ti + 1], v[ti + 1] };
            v2f v2 = { v[ti + 2], v[ti + 2] };
            v2f w;
            w.x = w0a.x; w.y = w0a.y; acc[ti][0] = fma2(v0, w, acc[ti][0]);
            w.x = w0a.z; w.y = w0a.w; acc[ti][1] = fma2(v0, w, acc[ti][1]);
            w.x = w0b.x; w.y = w0b.y; acc[ti][2] = fma2(v0, w, acc[ti][2]);
            w.x = w0b.z; w.y = w0b.w; acc[ti][3] = fma2(v0, w, acc[ti][3]);
            w.x = w1a.x; w.y = w1a.y; acc[ti][0] = fma2(v1, w, acc[ti][0]);
            w.x = w1a.z; w.y = w1a.w; acc[ti][1] = fma2(v1, w, acc[ti][1]);
            w.x = w1b.x; w.y = w1b.y; acc[ti][2] = fma2(v1, w, acc[ti][2]);
            w.x = w1b.z; w.y = w1b.w; acc[ti][3] = fma2(v1, w, acc[ti][3]);
            w.x = w2a.x; w.y = w2a.y; acc[ti][0] = fma2(v2, w, acc[ti][0]);
            w.x = w2a.z; w.y = w2a.w; acc[ti][1] = fma2(v2, w, acc[ti][1]);
            w.x = w2b.x; w.y = w2b.y; acc[ti][2] = fma2(v2, w, acc[ti][2]);
            w.x = w2b.z; w.y = w2b.w; acc[ti][3] = fma2(v2, w, acc[ti][3]);
        }
    }

    #pragma unroll
    for (int ti = 0; ti < 8; ++ti) {
        float* p = outp + (size_t)(tg * 8 + ti) * 512 + d0;
        reinterpret_cast<float4*>(p)[0] =
            make_float4(acc[ti][0].x, acc[ti][0].y, acc[ti][1].x, acc[ti][1].y);
        reinterpret_cast<float4*>(p)[1] =
            make_float4(acc[ti][2].x, acc[ti][2].y, acc[ti][3].x, acc[ti][3].y);
    }
}

__global__ __launch_bounds__(256) void delay_fir_kernel(
    const float* __restrict__ x,       // [32][4096][21]
    const float* __restrict__ conv_w,  // [24][8][3]
    const float* __restrict__ conv_b,  // [24]
    const float* __restrict__ lw,      // [8][8][3]
    const float* __restrict__ lb,      // [8]
    float* __restrict__ out)           // [32][4096][512]
{
    __shared__ float xs[CC * XSTR];
    __shared__ __align__(16) float wtc[24 * 32];
    __shared__ float biasc[32];

    const int tid = threadIdx.x;
    const int t0 = blockIdx.x * TT;
    const int b  = blockIdx.y;

    // stage weights, transposed to wtc[jk][vo] (vo = virtual output row, 0..31)
    for (int e = tid; e < 24 * 32; e += 256) {
        int jk = e >> 5, vo = e & 31;
        wtc[e] = (vo < 24) ? conv_w[vo * 24 + jk] : lw[(vo - 24) * 24 + jk];
    }
    if (tid < 32) biasc[tid] = (tid < 24) ? conv_b[tid] : lb[tid - 24];

    // stage x circularly: xs[c][s] = x[b][(t0-85+s) & 4095][c], s in [0,150)
    const float* xb = x + (size_t)b * (LL * CC);
    const int baset = t0 - 85;
    for (int e = tid; e < 150 * CC; e += 256) {
        int s = e / CC, c = e - s * CC;
        int time = (baset + s) & (LL - 1);
        xs[c * XSTR + s] = xb[time * CC + c];
    }
    __syncthreads();

    // lane -> output-channel group: og 0..62 -> (c = og/3, 8 conv outputs),
    // og 63 -> leftout (c=20, weight rows 24..31, d0=504)
    const int og = tid & 63;
    int c, o0, d0;
    if (og == 63) { c = 20; o0 = 24; d0 = 504; }
    else { c = og / 3; int osub = og - c * 3; o0 = osub * 8; d0 = c * 24 + osub * 8; }

    const float* xrow = &xs[c * XSTR];
    float* outp = out + ((size_t)b * LL + t0) * 512;
    const bool edge = (t0 == 0) | (t0 == TT) | (t0 == LL - TT);

    for (int it = 0; it < 2; ++it) {
        int tg = it * 4 + (tid >> 6);   // wave-uniform t-subgroup
        if (edge) compute_item<true >(xrow, wtc, biasc, outp, o0, d0, tg, t0);
        else      compute_item<false>(xrow, wtc, biasc, outp, o0, d0, tg, t0);
    }
}

extern "C" void kernel_launch(void* const* d_in, const int* in_sizes, int n_in,
                              void* d_out, int out_size, void* d_ws, size_t ws_size,
                              hipStream_t stream) {
    const float* x      = (const float*)d_in[0];
    const float* conv_w = (const float*)d_in[1];
    const float* conv_b = (const float*)d_in[2];
    const float* lw     = (const float*)d_in[3];
    const float* lb     = (const float*)d_in[4];
    float* out = (float*)d_out;

    dim3 grid(LL / TT, 32);  // (64 t-tiles, B)
    delay_fir_kernel<<<grid, 256, 0, stream>>>(x, conv_w, conv_b, lw, lb, out);
}

// Round 4
// 70.018 us; speedup vs baseline: 1.0450x; 1.0450x over previous
//
#include <hip/hip_runtime.h>

// Problem constants: B=32, L=4096, C=21, D=512, K=24, LO=8, M=7, TAO=12
#define LL 4096
#define CC 21
#define TT 64          // t-tile per block
#define XSTR 151       // LDS time stride (>= 150 staged slots, odd for bank spread)

typedef float v2f __attribute__((ext_vector_type(2)));
typedef float v4f __attribute__((ext_vector_type(4)));

__device__ __forceinline__ v2f fma2(v2f a, v2f b, v2f c) {
    return __builtin_elementwise_fma(a, b, c);
}

// Each lane computes a 4-d x 16-t output tile; a wave's 64 lanes cover a
// contiguous 256-float d-range, so every store instruction is a fully dense
// 1 KB (16 whole 64B lines) -> full-line writes, no TCC write-allocate fills.
// xrow = &xs[c*XSTR] (LDS circular x column), wtc = [24][32] weight table
// EDGE: zero-mask wrapped conv positions tt<84 (tiles t0 in {0,64,4032})
template<bool EDGE>
__device__ __forceinline__ void compute_item(
    const float* __restrict__ xrow, const float* __restrict__ wtc,
    const float* __restrict__ biasc, float* __restrict__ outp,
    int vo0, int d0, int tg, int t0)
{
    v2f acc[16][2];
    {
        v2f b0 = { biasc[vo0],     biasc[vo0 + 1] };
        v2f b1 = { biasc[vo0 + 2], biasc[vo0 + 3] };
        #pragma unroll
        for (int ti = 0; ti < 16; ++ti) { acc[ti][0] = b0; acc[ti][1] = b1; }
    }

    // mask is j-independent: zero when conv position tt=(t0+tg*16+s-1) mod L < 84
    bool msk[18];
    if (EDGE) {
        #pragma unroll
        for (int s = 0; s < 18; ++s)
            msk[s] = (((t0 + tg * 16 + s - 1) & (LL - 1)) < 84);
    }

    const int base = tg * 16 + 84;   // LDS slot of (row 0, k=0) at j=0

    #pragma unroll 1
    for (int j = 0; j < 8; ++j) {
        const float* wp = &wtc[(3 * j) * 32 + vo0];     // 16B-aligned
        float4 w0 = *reinterpret_cast<const float4*>(wp);
        float4 w1 = *reinterpret_cast<const float4*>(wp + 32);
        float4 w2 = *reinterpret_cast<const float4*>(wp + 64);

        // sliding window: 18 slots cover k=0..2, ti=0..15 for this j
        const float* vp = xrow + base - 12 * j;
        float v[18];
        #pragma unroll
        for (int s = 0; s < 18; ++s) {
            float t = vp[s];
            if (EDGE && msk[s]) t = 0.0f;
            v[s] = t;
        }

        #pragma unroll
        for (int ti = 0; ti < 16; ++ti) {
            v2f vv, w;
            vv.x = vv.y = v[ti];
            w.x = w0.x; w.y = w0.y; acc[ti][0] = fma2(vv, w, acc[ti][0]);
            w.x = w0.z; w.y = w0.w; acc[ti][1] = fma2(vv, w, acc[ti][1]);
            vv.x = vv.y = v[ti + 1];
            w.x = w1.x; w.y = w1.y; acc[ti][0] = fma2(vv, w, acc[ti][0]);
            w.x = w1.z; w.y = w1.w; acc[ti][1] = fma2(vv, w, acc[ti][1]);
            vv.x = vv.y = v[ti + 2];
            w.x = w2.x; w.y = w2.y; acc[ti][0] = fma2(vv, w, acc[ti][0]);
            w.x = w2.z; w.y = w2.w; acc[ti][1] = fma2(vv, w, acc[ti][1]);
        }
    }

    #pragma unroll
    for (int ti = 0; ti < 16; ++ti) {
        v4f r = { acc[ti][0].x, acc[ti][0].y, acc[ti][1].x, acc[ti][1].y };
        float* p = outp + (size_t)(tg * 16 + ti) * 512 + d0;
        __builtin_nontemporal_store(r, reinterpret_cast<v4f*>(p));
    }
}

__global__ __launch_bounds__(256) void delay_fir_kernel(
    const float* __restrict__ x,       // [32][4096][21]
    const float* __restrict__ conv_w,  // [24][8][3]
    const float* __restrict__ conv_b,  // [24]
    const float* __restrict__ lw,      // [8][8][3]
    const float* __restrict__ lb,      // [8]
    float* __restrict__ out)           // [32][4096][512]
{
    __shared__ float xs[CC * XSTR];
    __shared__ __align__(16) float wtc[24 * 32];
    __shared__ float biasc[32];

    const int tid = threadIdx.x;
    const int t0 = blockIdx.x * TT;
    const int b  = blockIdx.y;

    // stage weights, transposed to wtc[jk][vo] (vo<24: conv row o, 24..31: leftout)
    for (int e = tid; e < 24 * 32; e += 256) {
        int jk = e >> 5, vo = e & 31;
        wtc[e] = (vo < 24) ? conv_w[vo * 24 + jk] : lw[(vo - 24) * 24 + jk];
    }
    if (tid < 32) biasc[tid] = (tid < 24) ? conv_b[tid] : lb[tid - 24];

    // stage x circularly: xs[c][s] = x[b][(t0-85+s) & 4095][c], s in [0,150)
    const float* xb = x + (size_t)b * (LL * CC);
    const int baset = t0 - 85;
    for (int e = tid; e < 150 * CC; e += 256) {
        int s = e / CC, c = e - s * CC;
        int time = (baset + s) & (LL - 1);
        xs[c * XSTR + s] = xb[time * CC + c];
    }
    __syncthreads();

    // lane -> d mapping: wave w owns d-half h=w&1; lane l covers d0=256h+4l..+3.
    // 4-float groups never straddle a c boundary (24 % 4 == 0).
    const int l = tid & 63;
    const int w = tid >> 6;
    const int h = w & 1;
    const int d0 = 256 * h + 4 * l;
    int c, vo0;
    if (d0 >= 504) { c = 20; vo0 = 24 + (d0 - 504); }   // leftout rows
    else           { c = d0 / 24; vo0 = d0 - c * 24; }

    const float* xrow = &xs[c * XSTR];
    float* outp = out + ((size_t)b * LL + t0) * 512;
    const bool edge = (t0 == 0) | (t0 == TT) | (t0 == LL - TT);

    for (int it = 0; it < 2; ++it) {
        int tg = it * 2 + (w >> 1);   // wave-uniform t-subgroup (0..3)
        if (edge) compute_item<true >(xrow, wtc, biasc, outp, vo0, d0, tg, t0);
        else      compute_item<false>(xrow, wtc, biasc, outp, vo0, d0, tg, t0);
    }
}

extern "C" void kernel_launch(void* const* d_in, const int* in_sizes, int n_in,
                              void* d_out, int out_size, void* d_ws, size_t ws_size,
                              hipStream_t stream) {
    const float* x      = (const float*)d_in[0];
    const float* conv_w = (const float*)d_in[1];
    const float* conv_b = (const float*)d_in[2];
    const float* lw     = (const float*)d_in[3];
    const float* lb     = (const float*)d_in[4];
    float* out = (float*)d_out;

    dim3 grid(LL / TT, 32);  // (64 t-tiles, B)
    delay_fir_kernel<<<grid, 256, 0, stream>>>(x, conv_w, conv_b, lw, lb, out);
}

// Round 5
// 64.226 us; speedup vs baseline: 1.1392x; 1.0902x over previous
//
#include <hip/hip_runtime.h>

// Problem constants: B=32, L=4096, C=21, D=512, K=24, LO=8, M=7, TAO=12
#define LL 4096
#define CC 21
#define TT 64            // t-tile
#define NTB 4            // tiles per block (pipelined)
#define XSTR 151         // LDS time stride (>=150, odd for bank spread)
#define STG_N (150 * CC) // 3150 staged floats per tile
#define NSTG 13          // ceil(3150/256)

typedef float v2f __attribute__((ext_vector_type(2)));
typedef float v4f __attribute__((ext_vector_type(4)));

__device__ __forceinline__ v2f fma2(v2f a, v2f b, v2f c) {
    return __builtin_elementwise_fma(a, b, c);
}

// Issue the 13 global loads for the tile starting at conv base `baset` (= t0-85).
// Branchless wrap: ofs = baset*21 + e, corrected by ±LL*21 via e-thresholds.
__device__ __forceinline__ void prefetch_tile(const float* __restrict__ xb,
                                              int baset, int tid, float* pf) {
    const int lo21 = (0 - baset) * CC;    // e <  lo21 -> time wrapped negative
    const int hi21 = (LL - baset) * CC;   // e >= hi21 -> time wrapped past LL
    #pragma unroll
    for (int i = 0; i < NSTG; ++i) {
        int e = tid + 256 * i;
        if (e < STG_N) {
            int ofs = baset * CC + e;
            if (e < lo21)  ofs += LL * CC;
            if (e >= hi21) ofs -= LL * CC;
            pf[i] = xb[ofs];
        }
    }
}

__device__ __forceinline__ void write_tile(float* __restrict__ xsb, int tid,
                                           const int* ldsoff, const float* pf) {
    #pragma unroll
    for (int i = 0; i < NSTG; ++i) {
        int e = tid + 256 * i;
        if (e < STG_N) xsb[ldsoff[i]] = pf[i];
    }
}

// Each lane computes a 4-d x 16-t output tile; a wave's 64 lanes cover a
// contiguous 256-float d-range -> every store is a fully dense 1 KB.
// EDGE: zero-mask conv positions ptt = (t0+tg*16+s-1) mod L < 84.
template<bool EDGE>
__device__ __forceinline__ void compute_item(
    const float* __restrict__ xrow, const float* __restrict__ wtc,
    const float* __restrict__ biasc, float* __restrict__ outp,
    int vo0, int d0, int tg, int t0)
{
    v2f acc[16][2];
    {
        v2f b0 = { biasc[vo0],     biasc[vo0 + 1] };
        v2f b1 = { biasc[vo0 + 2], biasc[vo0 + 3] };
        #pragma unroll
        for (int ti = 0; ti < 16; ++ti) { acc[ti][0] = b0; acc[ti][1] = b1; }
    }

    bool msk[18];
    if (EDGE) {
        #pragma unroll
        for (int s = 0; s < 18; ++s)
            msk[s] = (((t0 + tg * 16 + s - 1) & (LL - 1)) < 84);
    }

    const int base = tg * 16 + 84;   // LDS slot of (row 0, k=0) at j=0

    #pragma unroll 1
    for (int j = 0; j < 8; ++j) {
        const float* wp = &wtc[(3 * j) * 32 + vo0];     // 16B-aligned
        float4 w0 = *reinterpret_cast<const float4*>(wp);
        float4 w1 = *reinterpret_cast<const float4*>(wp + 32);
        float4 w2 = *reinterpret_cast<const float4*>(wp + 64);

        const float* vp = xrow + base - 12 * j;
        float v[18];
        #pragma unroll
        for (int s = 0; s < 18; ++s) {
            float t = vp[s];
            if (EDGE && msk[s]) t = 0.0f;
            v[s] = t;
        }

        #pragma unroll
        for (int ti = 0; ti < 16; ++ti) {
            v2f vv, w;
            vv.x = vv.y = v[ti];
            w.x = w0.x; w.y = w0.y; acc[ti][0] = fma2(vv, w, acc[ti][0]);
            w.x = w0.z; w.y = w0.w; acc[ti][1] = fma2(vv, w, acc[ti][1]);
            vv.x = vv.y = v[ti + 1];
            w.x = w1.x; w.y = w1.y; acc[ti][0] = fma2(vv, w, acc[ti][0]);
            w.x = w1.z; w.y = w1.w; acc[ti][1] = fma2(vv, w, acc[ti][1]);
            vv.x = vv.y = v[ti + 2];
            w.x = w2.x; w.y = w2.y; acc[ti][0] = fma2(vv, w, acc[ti][0]);
            w.x = w2.z; w.y = w2.w; acc[ti][1] = fma2(vv, w, acc[ti][1]);
        }
    }

    #pragma unroll
    for (int ti = 0; ti < 16; ++ti) {
        v4f r = { acc[ti][0].x, acc[ti][0].y, acc[ti][1].x, acc[ti][1].y };
        float* p = outp + (size_t)(tg * 16 + ti) * 512 + d0;
        __builtin_nontemporal_store(r, reinterpret_cast<v4f*>(p));
    }
}

__global__ __launch_bounds__(256) void delay_fir_kernel(
    const float* __restrict__ x,       // [32][4096][21]
    const float* __restrict__ conv_w,  // [24][8][3]
    const float* __restrict__ conv_b,  // [24]
    const float* __restrict__ lw,      // [8][8][3]
    const float* __restrict__ lb,      // [8]
    float* __restrict__ out)           // [32][4096][512]
{
    __shared__ float xs[2][CC * XSTR];
    __shared__ __align__(16) float wtc[24 * 32];
    __shared__ float biasc[32];

    const int tid   = threadIdx.x;
    const int b     = blockIdx.y;
    const int tbase = blockIdx.x * (TT * NTB);

    // stage weights once per block, transposed to wtc[jk][vo]
    for (int e = tid; e < 24 * 32; e += 256) {
        int jk = e >> 5, vo = e & 31;
        wtc[e] = (vo < 24) ? conv_w[vo * 24 + jk] : lw[(vo - 24) * 24 + jk];
    }
    if (tid < 32) biasc[tid] = (tid < 24) ? conv_b[tid] : lb[tid - 24];

    const float* xb = x + (size_t)b * (LL * CC);

    // precompute LDS offsets for staging (static indexing -> registers)
    int ldsoff[NSTG];
    #pragma unroll
    for (int i = 0; i < NSTG; ++i) {
        int e = tid + 256 * i;
        int s = e / CC, c2 = e - s * CC;
        ldsoff[i] = c2 * XSTR + s;
    }

    // lane -> d mapping: wave w owns d-half h=w&1; lane l covers d0=256h+4l..+3
    const int l  = tid & 63;
    const int w  = tid >> 6;
    const int d0 = 256 * (w & 1) + 4 * l;
    int c, vo0;
    if (d0 >= 504) { c = 20; vo0 = 24 + (d0 - 504); }   // leftout rows 24..31
    else           { c = d0 / 24; vo0 = d0 - c * 24; }

    // prologue: stage tile 0
    float pf[NSTG];
    prefetch_tile(xb, tbase - 85, tid, pf);
    write_tile(xs[0], tid, ldsoff, pf);
    __syncthreads();

    #pragma unroll 1
    for (int tix = 0; tix < NTB; ++tix) {
        const int t0 = tbase + tix * TT;
        const float* xrow = &xs[tix & 1][c * XSTR];

        if (tix + 1 < NTB) prefetch_tile(xb, t0 + TT - 85, tid, pf);

        float* outp = out + ((size_t)b * LL + t0) * 512;
        const bool edge = (t0 == 0) | (t0 == TT) | (t0 == LL - TT);
        #pragma unroll 1
        for (int it = 0; it < 2; ++it) {
            int tg = it * 2 + (w >> 1);   // wave-uniform t-subgroup (0..3)
            if (edge) compute_item<true >(xrow, wtc, biasc, outp, vo0, d0, tg, t0);
            else      compute_item<false>(xrow, wtc, biasc, outp, vo0, d0, tg, t0);
        }

        if (tix + 1 < NTB) {
            write_tile(xs[(tix + 1) & 1], tid, ldsoff, pf);
            __syncthreads();
        }
    }
}

extern "C" void kernel_launch(void* const* d_in, const int* in_sizes, int n_in,
                              void* d_out, int out_size, void* d_ws, size_t ws_size,
                              hipStream_t stream) {
    const float* x      = (const float*)d_in[0];
    const float* conv_w = (const float*)d_in[1];
    const float* conv_b = (const float*)d_in[2];
    const float* lw     = (const float*)d_in[3];
    const float* lb     = (const float*)d_in[4];
    float* out = (float*)d_out;

    dim3 grid(LL / (TT * NTB), 32);  // (16, 32) = 512 blocks
    delay_fir_kernel<<<grid, 256, 0, stream>>>(x, conv_w, conv_b, lw, lb, out);
}

// Round 6
// 62.282 us; speedup vs baseline: 1.1747x; 1.0312x over previous
//
#include <hip/hip_runtime.h>

// Problem constants: B=32, L=4096, C=21, D=512, K=24, LO=8, M=7, TAO=12
#define LL 4096
#define CC 21
#define TT 64            // t-tile
#define NTB 2            // tiles per block (pipelined)
#define XSTR 151         // LDS time stride (>=150, odd for bank spread)
#define STG_N (150 * CC) // 3150 staged floats per tile
#define NSTG 13          // ceil(3150/256)

typedef float v2f __attribute__((ext_vector_type(2)));
typedef float v4f __attribute__((ext_vector_type(4)));

__device__ __forceinline__ v2f fma2(v2f a, v2f b, v2f c) {
    return __builtin_elementwise_fma(a, b, c);
}

// Issue the 13 global loads for the tile starting at conv base `baset` (= t0-85).
// Branchless wrap: ofs = baset*21 + e, corrected by ±LL*21 via e-thresholds.
__device__ __forceinline__ void prefetch_tile(const float* __restrict__ xb,
                                              int baset, int tid, float* pf) {
    const int lo21 = (0 - baset) * CC;    // e <  lo21 -> time wrapped negative
    const int hi21 = (LL - baset) * CC;   // e >= hi21 -> time wrapped past LL
    #pragma unroll
    for (int i = 0; i < NSTG; ++i) {
        int e = tid + 256 * i;
        if (e < STG_N) {
            int ofs = baset * CC + e;
            if (e < lo21)  ofs += LL * CC;
            if (e >= hi21) ofs -= LL * CC;
            pf[i] = xb[ofs];
        }
    }
}

__device__ __forceinline__ void write_tile(float* __restrict__ xsb, int tid,
                                           const int* ldsoff, const float* pf) {
    #pragma unroll
    for (int i = 0; i < NSTG; ++i) {
        int e = tid + 256 * i;
        if (e < STG_N) xsb[ldsoff[i]] = pf[i];
    }
}

// Each lane computes a 4-d x 16-t output tile; a wave's 64 lanes cover a
// contiguous 256-float d-range -> every store is a fully dense 1 KB.
// EDGE: zero-mask conv positions (t0+tg*16+s-1) mod L < 84.
template<bool EDGE>
__device__ __forceinline__ void compute_item(
    const float* __restrict__ xrow, const float* __restrict__ wtc,
    const float* __restrict__ biasc, float* __restrict__ outp,
    int vo0, int d0, int tg, int t0)
{
    v2f acc[16][2];
    {
        v2f b0 = { biasc[vo0],     biasc[vo0 + 1] };
        v2f b1 = { biasc[vo0 + 2], biasc[vo0 + 3] };
        #pragma unroll
        for (int ti = 0; ti < 16; ++ti) { acc[ti][0] = b0; acc[ti][1] = b1; }
    }

    bool msk[18];
    if (EDGE) {
        #pragma unroll
        for (int s = 0; s < 18; ++s)
            msk[s] = (((t0 + tg * 16 + s - 1) & (LL - 1)) < 84);
    }

    const int base = tg * 16 + 84;   // LDS slot of (row 0, k=0) at j=0

    #pragma unroll 1
    for (int j = 0; j < 8; ++j) {
        const float* wp = &wtc[(3 * j) * 32 + vo0];     // 16B-aligned
        float4 w0 = *reinterpret_cast<const float4*>(wp);
        float4 w1 = *reinterpret_cast<const float4*>(wp + 32);
        float4 w2 = *reinterpret_cast<const float4*>(wp + 64);

        const float* vp = xrow + base - 12 * j;
        float v[18];
        #pragma unroll
        for (int s = 0; s < 18; ++s) {
            float t = vp[s];
            if (EDGE && msk[s]) t = 0.0f;
            v[s] = t;
        }

        #pragma unroll
        for (int ti = 0; ti < 16; ++ti) {
            v2f vv, w;
            vv.x = vv.y = v[ti];
            w.x = w0.x; w.y = w0.y; acc[ti][0] = fma2(vv, w, acc[ti][0]);
            w.x = w0.z; w.y = w0.w; acc[ti][1] = fma2(vv, w, acc[ti][1]);
            vv.x = vv.y = v[ti + 1];
            w.x = w1.x; w.y = w1.y; acc[ti][0] = fma2(vv, w, acc[ti][0]);
            w.x = w1.z; w.y = w1.w; acc[ti][1] = fma2(vv, w, acc[ti][1]);
            vv.x = vv.y = v[ti + 2];
            w.x = w2.x; w.y = w2.y; acc[ti][0] = fma2(vv, w, acc[ti][0]);
            w.x = w2.z; w.y = w2.w; acc[ti][1] = fma2(vv, w, acc[ti][1]);
        }
    }

    #pragma unroll
    for (int ti = 0; ti < 16; ++ti) {
        v4f r = { acc[ti][0].x, acc[ti][0].y, acc[ti][1].x, acc[ti][1].y };
        float* p = outp + (size_t)(tg * 16 + ti) * 512 + d0;
        *reinterpret_cast<v4f*>(p) = r;   // regular store: L2 absorbs the burst
    }
}

__global__ __launch_bounds__(256) void delay_fir_kernel(
    const float* __restrict__ x,       // [32][4096][21]
    const float* __restrict__ conv_w,  // [24][8][3]
    const float* __restrict__ conv_b,  // [24]
    const float* __restrict__ lw,      // [8][8][3]
    const float* __restrict__ lb,      // [8]
    float* __restrict__ out)           // [32][4096][512]
{
    __shared__ float xs[2][CC * XSTR];
    __shared__ __align__(16) float wtc[24 * 32];
    __shared__ float biasc[32];

    const int tid   = threadIdx.x;
    const int b     = blockIdx.y;
    const int tbase = blockIdx.x * (TT * NTB);

    // stage weights once per block, transposed to wtc[jk][vo]
    for (int e = tid; e < 24 * 32; e += 256) {
        int jk = e >> 5, vo = e & 31;
        wtc[e] = (vo < 24) ? conv_w[vo * 24 + jk] : lw[(vo - 24) * 24 + jk];
    }
    if (tid < 32) biasc[tid] = (tid < 24) ? conv_b[tid] : lb[tid - 24];

    const float* xb = x + (size_t)b * (LL * CC);

    // precompute LDS offsets for staging (static indexing -> registers)
    int ldsoff[NSTG];
    #pragma unroll
    for (int i = 0; i < NSTG; ++i) {
        int e = tid + 256 * i;
        int s = e / CC, c2 = e - s * CC;
        ldsoff[i] = c2 * XSTR + s;
    }

    // lane -> d mapping: wave w owns d-half h=w&1; lane l covers d0=256h+4l..+3
    const int l  = tid & 63;
    const int w  = tid >> 6;
    const int d0 = 256 * (w & 1) + 4 * l;
    int c, vo0;
    if (d0 >= 504) { c = 20; vo0 = 24 + (d0 - 504); }   // leftout rows 24..31
    else           { c = d0 / 24; vo0 = d0 - c * 24; }

    // prologue: stage tile 0
    float pf[NSTG];
    prefetch_tile(xb, tbase - 85, tid, pf);
    write_tile(xs[0], tid, ldsoff, pf);
    __syncthreads();

    #pragma unroll 1
    for (int tix = 0; tix < NTB; ++tix) {
        const int t0 = tbase + tix * TT;
        const float* xrow = &xs[tix & 1][c * XSTR];

        if (tix + 1 < NTB) prefetch_tile(xb, t0 + TT - 85, tid, pf);

        float* outp = out + ((size_t)b * LL + t0) * 512;
        const bool edge = (t0 == 0) | (t0 == TT) | (t0 == LL - TT);
        #pragma unroll 1
        for (int it = 0; it < 2; ++it) {
            int tg = it * 2 + (w >> 1);   // wave-uniform t-subgroup (0..3)
            if (edge) compute_item<true >(xrow, wtc, biasc, outp, vo0, d0, tg, t0);
            else      compute_item<false>(xrow, wtc, biasc, outp, vo0, d0, tg, t0);
        }

        if (tix + 1 < NTB) {
            write_tile(xs[(tix + 1) & 1], tid, ldsoff, pf);
            __syncthreads();
        }
    }
}

extern "C" void kernel_launch(void* const* d_in, const int* in_sizes, int n_in,
                              void* d_out, int out_size, void* d_ws, size_t ws_size,
                              hipStream_t stream) {
    const float* x      = (const float*)d_in[0];
    const float* conv_w = (const float*)d_in[1];
    const float* conv_b = (const float*)d_in[2];
    const float* lw     = (const float*)d_in[3];
    const float* lb     = (const float*)d_in[4];
    float* out = (float*)d_out;

    dim3 grid(LL / (TT * NTB), 32);  // (32, 32) = 1024 blocks -> ~4 blocks/CU
    delay_fir_kernel<<<grid, 256, 0, stream>>>(x, conv_w, conv_b, lw, lb, out);
}